// Round 7
// baseline (1686.402 us; speedup 1.0000x reference)
//
#include <hip/hip_runtime.h>
#include <math.h>

// Problem constants
#define Bn 256
#define Tn 100
#define In 1024
#define Hn 2048
#define On 10
#define Kc (In + Hn)   // 3072 concatenated K

typedef short s8v  __attribute__((ext_vector_type(8)));   // 8 x bf16 (as raw shorts), 4 VGPRs
typedef unsigned short us4 __attribute__((ext_vector_type(4)));
typedef float f32x4 __attribute__((ext_vector_type(4)));

__device__ __forceinline__ unsigned short f2bf(float f) {
    unsigned int u = __float_as_uint(f);
    u += 0x7fffu + ((u >> 16) & 1u);   // round-to-nearest-even
    return (unsigned short)(u >> 16);
}

// tanh(x) = 1 - 2/(e^(2x)+1): v_exp_f32 + v_rcp_f32, ~2e-7 rel err (<< bf16 eps).
__device__ __forceinline__ float ftanh(float x) {
    float e = exp2f(x * 2.885390081777927f);          // e^(2x)
    return 1.f - 2.f * __builtin_amdgcn_rcpf(e + 1.f);
}

// ---- setup kernels -------------------------------------------------------

// x [B][T][I] fp32 -> bf16, 4 elems/thread
__global__ void conv_x_kernel(const float4* __restrict__ src, ushort4* __restrict__ dst) {
    int i = blockIdx.x * 256 + threadIdx.x;
    float4 v = src[i];
    ushort4 o;
    o.x = f2bf(v.x); o.y = f2bf(v.y); o.z = f2bf(v.z); o.w = f2bf(v.w);
    dst[i] = o;
}

// src [K][N=2048] fp32 -> dst[n][colOff + k] bf16  (builds B^T = [Win;W]^T rows)
__global__ void transpose_bf16_kernel(const float* __restrict__ src, unsigned short* __restrict__ dst,
                                      int N, int ld, int colOff) {
    __shared__ float tile[32][33];
    int k0 = blockIdx.x * 32;
    int n0 = blockIdx.y * 32;
    int c = threadIdx.x & 31;
    int r = threadIdx.x >> 5;            // 0..7
    #pragma unroll
    for (int i = 0; i < 32; i += 8)
        tile[r + i][c] = src[(size_t)(k0 + r + i) * N + n0 + c];
    __syncthreads();
    #pragma unroll
    for (int i = 0; i < 32; i += 8)
        dst[(size_t)(n0 + r + i) * ld + colOff + k0 + c] = f2bf(tile[c][r + i]);
}

// h0 -> h_all slot 0 (bf16); lin_w -> padded bf16 [16][2048]; zero barrier block
__global__ void small_conv_kernel(const float* __restrict__ h0, const float* __restrict__ lin_w,
                                  unsigned short* __restrict__ h_all0, unsigned short* __restrict__ lwb,
                                  unsigned int* __restrict__ bar) {
    int idx = blockIdx.x * 256 + threadIdx.x;
    if (idx < 512) bar[idx] = 0u;        // counters + master + epoch (re-zeroed every launch)
    if (idx < Bn * Hn) {
        h_all0[idx] = f2bf(h0[idx]);
    } else {
        int j = idx - Bn * Hn;           // < 16*2048 exactly (grid sized for it)
        int o = j >> 11;
        int k = j & 2047;
        lwb[j] = (o < On) ? f2bf(lin_w[o * Hn + k]) : (unsigned short)0;
    }
}

// ---- persistent scan -----------------------------------------------------
// 256 blocks x 512 thr (8 waves = 2/SIMD), 1 block/CU. Tile 64m x 32n;
// n XCD-pinned via blockIdx%8 (B^T slice L2-resident).
// R6/R7: R5's "B in registers" never materialized (VGPR_Count stayed 84 —
// regalloc remats loop-invariant loads). Fixes:
//  * asm volatile "+v" on every B fragment after preload: definition becomes
//    opaque -> cannot remat -> 96 VGPRs genuinely live all 100 steps.
//  * depth-2 rotating prefetch of the 8 h-chunks (A0/A1/A2).
//  * x-part: all 4 chunks' loads issued upfront in the cross-barrier window.
// Sync (proven R4/R5): relaxed agent write-through h stores; hierarchical
// barrier (8 group counters -> master -> epoch; relaxed-load polling).
__global__ __launch_bounds__(512, 2)
void scan_kernel(const unsigned short* __restrict__ xb,
                 const unsigned short* __restrict__ BTm,
                 unsigned short* __restrict__ h_all,
                 unsigned int* __restrict__ bar) {
    const int g = blockIdx.x;
    const int m0 = ((g >> 3) & 3) * 64;                 // 4 m-tiles
    const int n0 = ((g & 7) * 8 + (g >> 5)) * 32;       // 64 n-tiles, XCD-pinned
    const int w = threadIdx.x >> 6;                     // 0..7
    const int lane = threadIdx.x & 63;
    const int quad = lane >> 4;
    const int lr = lane & 15;

    __shared__ float red[4][64][36];                    // pad 36: 2-way banks (free)

    const unsigned short* bp0 = BTm + (size_t)(n0 + lr) * Kc;
    const unsigned short* bp1 = BTm + (size_t)(n0 + 16 + lr) * Kc;

    const size_t xrow = (size_t)Tn * In;                // x row stride (102400)

    unsigned int* grp_cnt = bar + (g & 7) * 32;         // 8 counters, 128B apart
    unsigned int* mst_cnt = bar + 256;
    unsigned int* epoch   = bar + 288;

    // ---- one-time B-fragment preload, pinned live via opaque asm ----
    s8v bx[4][2];                                       // x-region B frags
    s8v bh[8][2];                                       // h-region B frags
    #pragma unroll
    for (int c = 0; c < 4; ++c) {
        const int kq = w * 128 + c * 32 + quad * 8;
        bx[c][0] = *(const s8v*)(bp0 + kq);
        bx[c][1] = *(const s8v*)(bp1 + kq);
    }
    #pragma unroll
    for (int c = 0; c < 8; ++c) {
        const int kq = In + w * 256 + c * 32 + quad * 8;
        bh[c][0] = *(const s8v*)(bp0 + kq);
        bh[c][1] = *(const s8v*)(bp1 + kq);
    }
    #pragma unroll
    for (int c = 0; c < 4; ++c)
        asm volatile("" : "+v"(bx[c][0]), "+v"(bx[c][1]));
    #pragma unroll
    for (int c = 0; c < 8; ++c)
        asm volatile("" : "+v"(bh[c][0]), "+v"(bh[c][1]));

    f32x4 acc[4][2];
    #pragma unroll
    for (int mi = 0; mi < 4; ++mi)
        #pragma unroll
        for (int ni = 0; ni < 2; ++ni)
            acc[mi][ni] = (f32x4){0.f, 0.f, 0.f, 0.f};

    // ---- x-part for t=0: issue all 16 loads, then MFMA ----
    {
        const unsigned short* xbp = xb + (size_t)(m0 + lr) * xrow + w * 128 + quad * 8;
        s8v X[4][4];
        #pragma unroll
        for (int c = 0; c < 4; ++c) {
            const unsigned short* p = xbp + c * 32;
            X[c][0] = *(const s8v*)(p);
            X[c][1] = *(const s8v*)(p + 16 * xrow);
            X[c][2] = *(const s8v*)(p + 32 * xrow);
            X[c][3] = *(const s8v*)(p + 48 * xrow);
        }
        #pragma unroll
        for (int c = 0; c < 4; ++c) {
            #pragma unroll
            for (int mi = 0; mi < 4; ++mi) {
                acc[mi][0] = __builtin_amdgcn_mfma_f32_16x16x32_bf16(X[c][mi], bx[c][0], acc[mi][0], 0, 0, 0);
                acc[mi][1] = __builtin_amdgcn_mfma_f32_16x16x32_bf16(X[c][mi], bx[c][1], acc[mi][1], 0, 0, 0);
            }
        }
    }

    for (int t = 0; t < Tn; ++t) {
        // ---- h-part: depth-2 rotating prefetch over 8 chunks ----
        const unsigned short* hb = h_all + (size_t)t * (Bn * Hn)
                                 + (size_t)(m0 + lr) * Hn + w * 256 + quad * 8;
        s8v A0[4], A1[4];
        {
            const unsigned short* p = hb;
            A0[0] = *(const s8v*)(p);
            A0[1] = *(const s8v*)(p + 16 * Hn);
            A0[2] = *(const s8v*)(p + 32 * Hn);
            A0[3] = *(const s8v*)(p + 48 * Hn);
            p = hb + 32;
            A1[0] = *(const s8v*)(p);
            A1[1] = *(const s8v*)(p + 16 * Hn);
            A1[2] = *(const s8v*)(p + 32 * Hn);
            A1[3] = *(const s8v*)(p + 48 * Hn);
        }
        #pragma unroll
        for (int c = 0; c < 8; ++c) {
            s8v A2[4];
            if (c < 6) {
                const unsigned short* p = hb + (c + 2) * 32;
                A2[0] = *(const s8v*)(p);
                A2[1] = *(const s8v*)(p + 16 * Hn);
                A2[2] = *(const s8v*)(p + 32 * Hn);
                A2[3] = *(const s8v*)(p + 48 * Hn);
            }
            #pragma unroll
            for (int mi = 0; mi < 4; ++mi) {
                acc[mi][0] = __builtin_amdgcn_mfma_f32_16x16x32_bf16(A0[mi], bh[c][0], acc[mi][0], 0, 0, 0);
                acc[mi][1] = __builtin_amdgcn_mfma_f32_16x16x32_bf16(A0[mi], bh[c][1], acc[mi][1], 0, 0, 0);
            }
            #pragma unroll
            for (int j = 0; j < 4; ++j) A0[j] = A1[j];
            if (c < 6) {
                #pragma unroll
                for (int j = 0; j < 4; ++j) A1[j] = A2[j];
            }
        }

        // ---- LDS reduce: C/D layout row=quad*4+reg, col=lane&15 [m89/m91] ----
        if (w < 4) {
            #pragma unroll
            for (int mi = 0; mi < 4; ++mi)
                #pragma unroll
                for (int ni = 0; ni < 2; ++ni)
                    #pragma unroll
                    for (int rr = 0; rr < 4; ++rr)
                        red[w][mi * 16 + quad * 4 + rr][ni * 16 + lr] = acc[mi][ni][rr];
        }
        __syncthreads();
        if (w >= 4) {
            #pragma unroll
            for (int mi = 0; mi < 4; ++mi)
                #pragma unroll
                for (int ni = 0; ni < 2; ++ni)
                    #pragma unroll
                    for (int rr = 0; rr < 4; ++rr)
                        red[w - 4][mi * 16 + quad * 4 + rr][ni * 16 + lr] += acc[mi][ni][rr];
        }
        __syncthreads();

        {   // final reduce + tanh + agent-scope write-through store (8 B)
            int j = threadIdx.x << 2;
            int row = j >> 5;
            int c0 = j & 31;
            float4 s0 = *(const float4*)&red[0][row][c0];
            float4 s1 = *(const float4*)&red[1][row][c0];
            float4 s2 = *(const float4*)&red[2][row][c0];
            float4 s3 = *(const float4*)&red[3][row][c0];
            us4 o4;
            o4[0] = f2bf(ftanh(s0.x + s1.x + s2.x + s3.x));
            o4[1] = f2bf(ftanh(s0.y + s1.y + s2.y + s3.y));
            o4[2] = f2bf(ftanh(s0.z + s1.z + s2.z + s3.z));
            o4[3] = f2bf(ftanh(s0.w + s1.w + s2.w + s3.w));
            unsigned long long* dst = (unsigned long long*)
                (h_all + (size_t)(t + 1) * (Bn * Hn) + (size_t)(m0 + row) * Hn + n0 + c0);
            __hip_atomic_store(dst, __builtin_bit_cast(unsigned long long, o4),
                               __ATOMIC_RELAXED, __HIP_MEMORY_SCOPE_AGENT);
        }

        if (t < Tn - 1) {
            // ---- cross-barrier fill: next step's x-part (16 loads upfront) ----
            #pragma unroll
            for (int mi = 0; mi < 4; ++mi)
                #pragma unroll
                for (int ni = 0; ni < 2; ++ni)
                    acc[mi][ni] = (f32x4){0.f, 0.f, 0.f, 0.f};
            const unsigned short* xbp = xb + (size_t)(t + 1) * In
                                      + (size_t)(m0 + lr) * xrow + w * 128 + quad * 8;
            s8v X[4][4];
            #pragma unroll
            for (int c = 0; c < 4; ++c) {
                const unsigned short* p = xbp + c * 32;
                X[c][0] = *(const s8v*)(p);
                X[c][1] = *(const s8v*)(p + 16 * xrow);
                X[c][2] = *(const s8v*)(p + 32 * xrow);
                X[c][3] = *(const s8v*)(p + 48 * xrow);
            }
            #pragma unroll
            for (int c = 0; c < 4; ++c) {
                #pragma unroll
                for (int mi = 0; mi < 4; ++mi) {
                    acc[mi][0] = __builtin_amdgcn_mfma_f32_16x16x32_bf16(X[c][mi], bx[c][0], acc[mi][0], 0, 0, 0);
                    acc[mi][1] = __builtin_amdgcn_mfma_f32_16x16x32_bf16(X[c][mi], bx[c][1], acc[mi][1], 0, 0, 0);
                }
            }

            __syncthreads();                             // h stores drained (vmcnt0)
            if (threadIdx.x == 0) {
                const unsigned int tp1 = (unsigned int)(t + 1);
                unsigned int old = __hip_atomic_fetch_add(grp_cnt, 1u, __ATOMIC_RELAXED,
                                                          __HIP_MEMORY_SCOPE_AGENT);
                if (old == 32u * tp1 - 1u) {
                    unsigned int mo = __hip_atomic_fetch_add(mst_cnt, 1u, __ATOMIC_RELAXED,
                                                             __HIP_MEMORY_SCOPE_AGENT);
                    if (mo == 8u * tp1 - 1u)
                        __hip_atomic_store(epoch, tp1, __ATOMIC_RELAXED,
                                           __HIP_MEMORY_SCOPE_AGENT);
                }
                while (__hip_atomic_load(epoch, __ATOMIC_RELAXED,
                                         __HIP_MEMORY_SCOPE_AGENT) < tp1)
                    __builtin_amdgcn_s_sleep(2);
            }
            __syncthreads();
        }
    }
}

// ---- output projection ---------------------------------------------------
// y[b][t][o] = h_all[t+1][b][:] . lin_w[o][:] + lin_b[o]. One 16-row wave per 16 (t,b) rows.
__global__ __launch_bounds__(256)
void gemm2_kernel(const unsigned short* __restrict__ h_all, const unsigned short* __restrict__ lwb,
                  const float* __restrict__ lb, float* __restrict__ y) {
    int gw = blockIdx.x * 4 + (threadIdx.x >> 6);       // 0..1599
    int lane = threadIdx.x & 63, quad = lane >> 4, lr = lane & 15;
    int m0 = gw * 16;
    int t = m0 >> 8;
    int b0 = m0 & 255;
    const unsigned short* ah = h_all + ((size_t)(t + 1) * Bn + b0 + lr) * Hn + quad * 8;
    const unsigned short* bh = lwb + (size_t)lr * Hn + quad * 8;
    f32x4 acc0 = {0.f, 0.f, 0.f, 0.f}, acc1 = {0.f, 0.f, 0.f, 0.f};
    #pragma unroll
    for (int k0 = 0; k0 < Hn; k0 += 64) {
        s8v a0 = *(const s8v*)(ah + k0);
        s8v b0 = *(const s8v*)(bh + k0);
        acc0 = __builtin_amdgcn_mfma_f32_16x16x32_bf16(a0, b0, acc0, 0, 0, 0);
        s8v a1 = *(const s8v*)(ah + k0 + 32);
        s8v b1 = *(const s8v*)(bh + k0 + 32);
        acc1 = __builtin_amdgcn_mfma_f32_16x16x32_bf16(a1, b1, acc1, 0, 0, 0);
    }
    acc0 = acc0 + acc1;
    if (lr < On) {
        float bias = lb[lr];
        #pragma unroll
        for (int rr = 0; rr < 4; ++rr) {
            int b = b0 + quad * 4 + rr;
            y[(size_t)b * (Tn * On) + t * On + lr] = acc0[rr] + bias;
        }
    }
}

// ---- host ----------------------------------------------------------------

extern "C" void kernel_launch(void* const* d_in, const int* in_sizes, int n_in,
                              void* d_out, int out_size, void* d_ws, size_t ws_size,
                              hipStream_t stream) {
    const float* x   = (const float*)d_in[0];
    const float* h0  = (const float*)d_in[1];
    const float* Win = (const float*)d_in[2];
    const float* W   = (const float*)d_in[3];
    const float* lw  = (const float*)d_in[4];
    const float* lb  = (const float*)d_in[5];
    float* y = (float*)d_out;

    // ws layout (bf16 elems): ~171 MB total
    unsigned short* ws    = (unsigned short*)d_ws;
    unsigned short* xb    = ws;                                  // 26,214,400 elems
    unsigned short* BTm   = xb + (size_t)Bn * Tn * In;           //  6,291,456 elems [2048][3072]
    unsigned short* h_all = BTm + (size_t)Hn * Kc;               // 52,953,088 elems [(T+1)][B][H]
    unsigned short* lwb   = h_all + (size_t)(Tn + 1) * Bn * Hn;  //     32,768 elems [16][2048]
    unsigned int*   bar   = (unsigned int*)(lwb + 32768);        // 512 uints barrier block

    conv_x_kernel<<<25600, 256, 0, stream>>>((const float4*)x, (ushort4*)xb);
    transpose_bf16_kernel<<<dim3(32, 64), 256, 0, stream>>>(Win, BTm, Hn, Kc, 0);
    transpose_bf16_kernel<<<dim3(64, 64), 256, 0, stream>>>(W, BTm, Hn, Kc, In);
    small_conv_kernel<<<2176, 256, 0, stream>>>(h0, lw, h_all, lwb, bar);

    scan_kernel<<<256, 512, 0, stream>>>(xb, BTm, h_all, bar);

    gemm2_kernel<<<400, 256, 0, stream>>>(h_all, lwb, lb, y);
}

// Round 8
// 1588.321 us; speedup vs baseline: 1.0618x; 1.0618x over previous
//
#include <hip/hip_runtime.h>
#include <math.h>

// Problem constants
#define Bn 256
#define Tn 100
#define In 1024
#define Hn 2048
#define On 10
#define Kc (In + Hn)   // 3072 concatenated K

typedef short s8v  __attribute__((ext_vector_type(8)));   // 8 x bf16 (as raw shorts), 4 VGPRs
typedef unsigned short us4 __attribute__((ext_vector_type(4)));
typedef float f32x4 __attribute__((ext_vector_type(4)));

__device__ __forceinline__ unsigned short f2bf(float f) {
    unsigned int u = __float_as_uint(f);
    u += 0x7fffu + ((u >> 16) & 1u);   // round-to-nearest-even
    return (unsigned short)(u >> 16);
}

// tanh(x) = 1 - 2/(e^(2x)+1): v_exp_f32 + v_rcp_f32, ~2e-7 rel err (<< bf16 eps).
__device__ __forceinline__ float ftanh(float x) {
    float e = exp2f(x * 2.885390081777927f);          // e^(2x)
    return 1.f - 2.f * __builtin_amdgcn_rcpf(e + 1.f);
}

// ---- setup kernels -------------------------------------------------------

// x [B][T][I] fp32 -> bf16, 4 elems/thread
__global__ void conv_x_kernel(const float4* __restrict__ src, ushort4* __restrict__ dst) {
    int i = blockIdx.x * 256 + threadIdx.x;
    float4 v = src[i];
    ushort4 o;
    o.x = f2bf(v.x); o.y = f2bf(v.y); o.z = f2bf(v.z); o.w = f2bf(v.w);
    dst[i] = o;
}

// src [K][N=2048] fp32 -> dst[n][colOff + k] bf16  (builds B^T = [Win;W]^T rows)
__global__ void transpose_bf16_kernel(const float* __restrict__ src, unsigned short* __restrict__ dst,
                                      int N, int ld, int colOff) {
    __shared__ float tile[32][33];
    int k0 = blockIdx.x * 32;
    int n0 = blockIdx.y * 32;
    int c = threadIdx.x & 31;
    int r = threadIdx.x >> 5;            // 0..7
    #pragma unroll
    for (int i = 0; i < 32; i += 8)
        tile[r + i][c] = src[(size_t)(k0 + r + i) * N + n0 + c];
    __syncthreads();
    #pragma unroll
    for (int i = 0; i < 32; i += 8)
        dst[(size_t)(n0 + r + i) * ld + colOff + k0 + c] = f2bf(tile[c][r + i]);
}

// h0 -> h_all slot 0 (bf16); lin_w -> padded bf16 [16][2048]; zero barrier block
__global__ void small_conv_kernel(const float* __restrict__ h0, const float* __restrict__ lin_w,
                                  unsigned short* __restrict__ h_all0, unsigned short* __restrict__ lwb,
                                  unsigned int* __restrict__ bar) {
    int idx = blockIdx.x * 256 + threadIdx.x;
    if (idx < 512) bar[idx] = 0u;        // counters/master/epoch/init/pop (re-zeroed every launch)
    if (idx < Bn * Hn) {
        h_all0[idx] = f2bf(h0[idx]);
    } else {
        int j = idx - Bn * Hn;           // < 16*2048 exactly (grid sized for it)
        int o = j >> 11;
        int k = j & 2047;
        lwb[j] = (o < On) ? f2bf(lin_w[o * Hn + k]) : (unsigned short)0;
    }
}

// ---- persistent scan -----------------------------------------------------
// 256 blocks x 512 thr (8 waves = 2/SIMD), 1 block/CU. Tile 64m x 32n;
// n XCD-pinned via blockIdx%8 (B^T slice L2 locality — perf heuristic only).
// Compute loop = R5's best (plain chunk loads, compiler-scheduled; VGPR-depth
// engineering in R6/R7 regressed and is reverted).
//
// R8 coherence redesign (R7 counters: WRITE_SIZE=103MB -> ALL h stores hit
// HBM; FETCH 620MB -> 5.7MB/step of h re-fetched FROM HBM; the h broadcast
// round-trips through HBM at ~900cyc inside the serial inter-step chain):
//  * h writes: plain stores -> dirty in writer XCD's L2.
//  * per-XCD flush: last-arriving block on each PHYSICAL XCD (real XCC_ID via
//    s_getreg, m09; populations measured at init — blockIdx%8 mapping is NOT
//    trusted for correctness) does its master fetch_add with RELEASE ->
//    one buffer_wbl2 per XCD per step (writeback-retain: B^T/x stay cached),
//    pushing h to L3 where readers hit at ~L3 latency instead of HBM.
//  * readers: no acquire anywhere (h[t+1] lines are first-touch per step;
//    launch-time invalidate killed poison copies) -> no buffer_inv ever.
__global__ __launch_bounds__(512, 2)
void scan_kernel(const unsigned short* __restrict__ xb,
                 const unsigned short* __restrict__ BTm,
                 unsigned short* __restrict__ h_all,
                 unsigned int* __restrict__ bar) {
    const int g = blockIdx.x;
    const int m0 = ((g >> 3) & 3) * 64;                 // 4 m-tiles
    const int n0 = ((g & 7) * 8 + (g >> 5)) * 32;       // 64 n-tiles
    const int w = threadIdx.x >> 6;                     // 0..7
    const int lane = threadIdx.x & 63;
    const int quad = lane >> 4;
    const int lr = lane & 15;

    __shared__ float red[4][64][36];                    // pad 36: 2-way banks (free)

    const unsigned short* bp0 = BTm + (size_t)(n0 + lr) * Kc;
    const unsigned short* bp1 = BTm + (size_t)(n0 + 16 + lr) * Kc;

    const size_t xrow = (size_t)Tn * In;                // x row stride (102400)

    unsigned int* mst_cnt = bar + 256;
    unsigned int* epoch   = bar + 288;
    unsigned int* initcnt = bar + 320;
    unsigned int* pop     = bar + 384;                  // pop[0..7], one line

    // ---- init: measure per-XCD populations (once), thread 0 only ----------
    unsigned int my_xcd = 0, my_pop = 0, n_xcd = 0;
    unsigned int* grp_cnt = bar;
    if (threadIdx.x == 0) {
        unsigned int x_id;
        asm volatile("s_getreg_b32 %0, hwreg(20, 0, 32)" : "=s"(x_id));  // HW_REG_XCC_ID
        my_xcd = x_id & 7u;
        grp_cnt = bar + my_xcd * 32;                    // counters 128B apart
        __hip_atomic_fetch_add(pop + my_xcd, 1u, __ATOMIC_RELAXED, __HIP_MEMORY_SCOPE_AGENT);
        __hip_atomic_fetch_add(initcnt, 1u, __ATOMIC_RELAXED, __HIP_MEMORY_SCOPE_AGENT);
        while (__hip_atomic_load(initcnt, __ATOMIC_RELAXED, __HIP_MEMORY_SCOPE_AGENT) < 256u)
            __builtin_amdgcn_s_sleep(2);
        #pragma unroll
        for (int i = 0; i < 8; ++i) {
            unsigned int p = __hip_atomic_load(pop + i, __ATOMIC_RELAXED, __HIP_MEMORY_SCOPE_AGENT);
            if (i == (int)my_xcd) my_pop = p;
            if (p != 0u) ++n_xcd;
        }
    }

    // ---- one-time B-fragment preload (compiler may cache or re-load) ------
    s8v bx[4][2];                                       // x-region B frags
    s8v bh[8][2];                                       // h-region B frags
    #pragma unroll
    for (int c = 0; c < 4; ++c) {
        const int kq = w * 128 + c * 32 + quad * 8;
        bx[c][0] = *(const s8v*)(bp0 + kq);
        bx[c][1] = *(const s8v*)(bp1 + kq);
    }
    #pragma unroll
    for (int c = 0; c < 8; ++c) {
        const int kq = In + w * 256 + c * 32 + quad * 8;
        bh[c][0] = *(const s8v*)(bp0 + kq);
        bh[c][1] = *(const s8v*)(bp1 + kq);
    }

    f32x4 acc[4][2];
    #pragma unroll
    for (int mi = 0; mi < 4; ++mi)
        #pragma unroll
        for (int ni = 0; ni < 2; ++ni)
            acc[mi][ni] = (f32x4){0.f, 0.f, 0.f, 0.f};

    // ---- x-part for t=0 ----
    {
        const unsigned short* xt = xb;
        #pragma unroll
        for (int c = 0; c < 4; ++c) {
            const int kq = w * 128 + c * 32 + quad * 8;
            const unsigned short* arow = xt + kq + (size_t)(m0 + lr) * xrow;
            s8v a0 = *(const s8v*)(arow);
            s8v a1 = *(const s8v*)(arow + 16 * xrow);
            s8v a2 = *(const s8v*)(arow + 32 * xrow);
            s8v a3 = *(const s8v*)(arow + 48 * xrow);
            acc[0][0] = __builtin_amdgcn_mfma_f32_16x16x32_bf16(a0, bx[c][0], acc[0][0], 0, 0, 0);
            acc[1][0] = __builtin_amdgcn_mfma_f32_16x16x32_bf16(a1, bx[c][0], acc[1][0], 0, 0, 0);
            acc[2][0] = __builtin_amdgcn_mfma_f32_16x16x32_bf16(a2, bx[c][0], acc[2][0], 0, 0, 0);
            acc[3][0] = __builtin_amdgcn_mfma_f32_16x16x32_bf16(a3, bx[c][0], acc[3][0], 0, 0, 0);
            acc[0][1] = __builtin_amdgcn_mfma_f32_16x16x32_bf16(a0, bx[c][1], acc[0][1], 0, 0, 0);
            acc[1][1] = __builtin_amdgcn_mfma_f32_16x16x32_bf16(a1, bx[c][1], acc[1][1], 0, 0, 0);
            acc[2][1] = __builtin_amdgcn_mfma_f32_16x16x32_bf16(a2, bx[c][1], acc[2][1], 0, 0, 0);
            acc[3][1] = __builtin_amdgcn_mfma_f32_16x16x32_bf16(a3, bx[c][1], acc[3][1], 0, 0, 0);
        }
    }

    for (int t = 0; t < Tn; ++t) {
        // ---- h-part (gated on barrier of step t-1) ----
        const unsigned short* hprev = h_all + (size_t)t * (Bn * Hn);
        #pragma unroll
        for (int c = 0; c < 8; ++c) {
            const int kq = w * 256 + c * 32 + quad * 8;            // offset inside h
            const unsigned short* arow = hprev + kq + (size_t)(m0 + lr) * Hn;
            s8v a0 = *(const s8v*)(arow);
            s8v a1 = *(const s8v*)(arow + 16 * Hn);
            s8v a2 = *(const s8v*)(arow + 32 * Hn);
            s8v a3 = *(const s8v*)(arow + 48 * Hn);
            acc[0][0] = __builtin_amdgcn_mfma_f32_16x16x32_bf16(a0, bh[c][0], acc[0][0], 0, 0, 0);
            acc[1][0] = __builtin_amdgcn_mfma_f32_16x16x32_bf16(a1, bh[c][0], acc[1][0], 0, 0, 0);
            acc[2][0] = __builtin_amdgcn_mfma_f32_16x16x32_bf16(a2, bh[c][0], acc[2][0], 0, 0, 0);
            acc[3][0] = __builtin_amdgcn_mfma_f32_16x16x32_bf16(a3, bh[c][0], acc[3][0], 0, 0, 0);
            acc[0][1] = __builtin_amdgcn_mfma_f32_16x16x32_bf16(a0, bh[c][1], acc[0][1], 0, 0, 0);
            acc[1][1] = __builtin_amdgcn_mfma_f32_16x16x32_bf16(a1, bh[c][1], acc[1][1], 0, 0, 0);
            acc[2][1] = __builtin_amdgcn_mfma_f32_16x16x32_bf16(a2, bh[c][1], acc[2][1], 0, 0, 0);
            acc[3][1] = __builtin_amdgcn_mfma_f32_16x16x32_bf16(a3, bh[c][1], acc[3][1], 0, 0, 0);
        }

        // ---- LDS reduce: C/D layout row=quad*4+reg, col=lane&15 [m89/m91] ----
        if (w < 4) {
            #pragma unroll
            for (int mi = 0; mi < 4; ++mi)
                #pragma unroll
                for (int ni = 0; ni < 2; ++ni)
                    #pragma unroll
                    for (int rr = 0; rr < 4; ++rr)
                        red[w][mi * 16 + quad * 4 + rr][ni * 16 + lr] = acc[mi][ni][rr];
        }
        __syncthreads();
        if (w >= 4) {
            #pragma unroll
            for (int mi = 0; mi < 4; ++mi)
                #pragma unroll
                for (int ni = 0; ni < 2; ++ni)
                    #pragma unroll
                    for (int rr = 0; rr < 4; ++rr)
                        red[w - 4][mi * 16 + quad * 4 + rr][ni * 16 + lr] += acc[mi][ni][rr];
        }
        __syncthreads();

        {   // final reduce + tanh + PLAIN bf16 store (dirty in local L2)
            int j = threadIdx.x << 2;
            int row = j >> 5;
            int c0 = j & 31;
            float4 s0 = *(const float4*)&red[0][row][c0];
            float4 s1 = *(const float4*)&red[1][row][c0];
            float4 s2 = *(const float4*)&red[2][row][c0];
            float4 s3 = *(const float4*)&red[3][row][c0];
            us4 o4;
            o4[0] = f2bf(ftanh(s0.x + s1.x + s2.x + s3.x));
            o4[1] = f2bf(ftanh(s0.y + s1.y + s2.y + s3.y));
            o4[2] = f2bf(ftanh(s0.z + s1.z + s2.z + s3.z));
            o4[3] = f2bf(ftanh(s0.w + s1.w + s2.w + s3.w));
            *(us4*)(h_all + (size_t)(t + 1) * (Bn * Hn) + (size_t)(m0 + row) * Hn + n0 + c0) = o4;
        }

        if (t < Tn - 1) {
            // ---- cross-barrier fill: next step's x-part ----
            #pragma unroll
            for (int mi = 0; mi < 4; ++mi)
                #pragma unroll
                for (int ni = 0; ni < 2; ++ni)
                    acc[mi][ni] = (f32x4){0.f, 0.f, 0.f, 0.f};
            const unsigned short* xt = xb + (size_t)(t + 1) * In;
            #pragma unroll
            for (int c = 0; c < 4; ++c) {
                const int kq = w * 128 + c * 32 + quad * 8;
                const unsigned short* arow = xt + kq + (size_t)(m0 + lr) * xrow;
                s8v a0 = *(const s8v*)(arow);
                s8v a1 = *(const s8v*)(arow + 16 * xrow);
                s8v a2 = *(const s8v*)(arow + 32 * xrow);
                s8v a3 = *(const s8v*)(arow + 48 * xrow);
                acc[0][0] = __builtin_amdgcn_mfma_f32_16x16x32_bf16(a0, bx[c][0], acc[0][0], 0, 0, 0);
                acc[1][0] = __builtin_amdgcn_mfma_f32_16x16x32_bf16(a1, bx[c][0], acc[1][0], 0, 0, 0);
                acc[2][0] = __builtin_amdgcn_mfma_f32_16x16x32_bf16(a2, bx[c][0], acc[2][0], 0, 0, 0);
                acc[3][0] = __builtin_amdgcn_mfma_f32_16x16x32_bf16(a3, bx[c][0], acc[3][0], 0, 0, 0);
                acc[0][1] = __builtin_amdgcn_mfma_f32_16x16x32_bf16(a0, bx[c][1], acc[0][1], 0, 0, 0);
                acc[1][1] = __builtin_amdgcn_mfma_f32_16x16x32_bf16(a1, bx[c][1], acc[1][1], 0, 0, 0);
                acc[2][1] = __builtin_amdgcn_mfma_f32_16x16x32_bf16(a2, bx[c][1], acc[2][1], 0, 0, 0);
                acc[3][1] = __builtin_amdgcn_mfma_f32_16x16x32_bf16(a3, bx[c][1], acc[3][1], 0, 0, 0);
            }

            __syncthreads();                             // h stores drained into local L2 (vmcnt0)
            if (threadIdx.x == 0) {
                const unsigned int tp1 = (unsigned int)(t + 1);
                unsigned int old = __hip_atomic_fetch_add(grp_cnt, 1u, __ATOMIC_RELAXED,
                                                          __HIP_MEMORY_SCOPE_AGENT);
                if (old == my_pop * tp1 - 1u) {
                    // last block on THIS physical XCD: release -> buffer_wbl2
                    // (flushes all 32 blocks' dirty h lines from this L2 to L3)
                    unsigned int mo = __hip_atomic_fetch_add(mst_cnt, 1u, __ATOMIC_RELEASE,
                                                             __HIP_MEMORY_SCOPE_AGENT);
                    if (mo == n_xcd * tp1 - 1u)
                        __hip_atomic_store(epoch, tp1, __ATOMIC_RELAXED,
                                           __HIP_MEMORY_SCOPE_AGENT);
                }
                while (__hip_atomic_load(epoch, __ATOMIC_RELAXED,
                                         __HIP_MEMORY_SCOPE_AGENT) < tp1)
                    __builtin_amdgcn_s_sleep(2);
            }
            __syncthreads();
        }
    }
}

// ---- output projection ---------------------------------------------------
// y[b][t][o] = h_all[t+1][b][:] . lin_w[o][:] + lin_b[o]. One 16-row wave per 16 (t,b) rows.
__global__ __launch_bounds__(256)
void gemm2_kernel(const unsigned short* __restrict__ h_all, const unsigned short* __restrict__ lwb,
                  const float* __restrict__ lb, float* __restrict__ y) {
    int gw = blockIdx.x * 4 + (threadIdx.x >> 6);       // 0..1599
    int lane = threadIdx.x & 63, quad = lane >> 4, lr = lane & 15;
    int m0 = gw * 16;
    int t = m0 >> 8;
    int b0 = m0 & 255;
    const unsigned short* ah = h_all + ((size_t)(t + 1) * Bn + b0 + lr) * Hn + quad * 8;
    const unsigned short* bh = lwb + (size_t)lr * Hn + quad * 8;
    f32x4 acc0 = {0.f, 0.f, 0.f, 0.f}, acc1 = {0.f, 0.f, 0.f, 0.f};
    #pragma unroll
    for (int k0 = 0; k0 < Hn; k0 += 64) {
        s8v a0 = *(const s8v*)(ah + k0);
        s8v b0 = *(const s8v*)(bh + k0);
        acc0 = __builtin_amdgcn_mfma_f32_16x16x32_bf16(a0, b0, acc0, 0, 0, 0);
        s8v a1 = *(const s8v*)(ah + k0 + 32);
        s8v b1 = *(const s8v*)(bh + k0 + 32);
        acc1 = __builtin_amdgcn_mfma_f32_16x16x32_bf16(a1, b1, acc1, 0, 0, 0);
    }
    acc0 = acc0 + acc1;
    if (lr < On) {
        float bias = lb[lr];
        #pragma unroll
        for (int rr = 0; rr < 4; ++rr) {
            int b = b0 + quad * 4 + rr;
            y[(size_t)b * (Tn * On) + t * On + lr] = acc0[rr] + bias;
        }
    }
}

// ---- host ----------------------------------------------------------------

extern "C" void kernel_launch(void* const* d_in, const int* in_sizes, int n_in,
                              void* d_out, int out_size, void* d_ws, size_t ws_size,
                              hipStream_t stream) {
    const float* x   = (const float*)d_in[0];
    const float* h0  = (const float*)d_in[1];
    const float* Win = (const float*)d_in[2];
    const float* W   = (const float*)d_in[3];
    const float* lw  = (const float*)d_in[4];
    const float* lb  = (const float*)d_in[5];
    float* y = (float*)d_out;

    // ws layout (bf16 elems): ~171 MB total
    unsigned short* ws    = (unsigned short*)d_ws;
    unsigned short* xb    = ws;                                  // 26,214,400 elems
    unsigned short* BTm   = xb + (size_t)Bn * Tn * In;           //  6,291,456 elems [2048][3072]
    unsigned short* h_all = BTm + (size_t)Hn * Kc;               // 52,953,088 elems [(T+1)][B][H]
    unsigned short* lwb   = h_all + (size_t)(Tn + 1) * Bn * Hn;  //     32,768 elems [16][2048]
    unsigned int*   bar   = (unsigned int*)(lwb + 32768);        // 512 uints barrier block

    conv_x_kernel<<<25600, 256, 0, stream>>>((const float4*)x, (ushort4*)xb);
    transpose_bf16_kernel<<<dim3(32, 64), 256, 0, stream>>>(Win, BTm, Hn, Kc, 0);
    transpose_bf16_kernel<<<dim3(64, 64), 256, 0, stream>>>(W, BTm, Hn, Kc, In);
    small_conv_kernel<<<2176, 256, 0, stream>>>(h0, lw, h_all, lwb, bar);

    scan_kernel<<<256, 512, 0, stream>>>(xb, BTm, h_all, bar);

    gemm2_kernel<<<400, 256, 0, stream>>>(h_all, lwb, lb, y);
}

// Round 9
// 1542.207 us; speedup vs baseline: 1.0935x; 1.0299x over previous
//
#include <hip/hip_runtime.h>
#include <math.h>

// Problem constants
#define Bn 256
#define Tn 100
#define In 1024
#define Hn 2048
#define On 10
#define Kc (In + Hn)   // 3072 concatenated K

typedef short s8v  __attribute__((ext_vector_type(8)));   // 8 x bf16 (as raw shorts), 4 VGPRs
typedef unsigned short us4 __attribute__((ext_vector_type(4)));
typedef float f32x4 __attribute__((ext_vector_type(4)));

__device__ __forceinline__ unsigned short f2bf(float f) {
    unsigned int u = __float_as_uint(f);
    u += 0x7fffu + ((u >> 16) & 1u);   // round-to-nearest-even
    return (unsigned short)(u >> 16);
}

// tanh(x) = 1 - 2/(e^(2x)+1): v_exp_f32 + v_rcp_f32, ~2e-7 rel err (<< bf16 eps).
__device__ __forceinline__ float ftanh(float x) {
    float e = exp2f(x * 2.885390081777927f);          // e^(2x)
    return 1.f - 2.f * __builtin_amdgcn_rcpf(e + 1.f);
}

// ---- setup kernels -------------------------------------------------------

// x [B][T][I] fp32 -> bf16, 4 elems/thread
__global__ void conv_x_kernel(const float4* __restrict__ src, ushort4* __restrict__ dst) {
    int i = blockIdx.x * 256 + threadIdx.x;
    float4 v = src[i];
    ushort4 o;
    o.x = f2bf(v.x); o.y = f2bf(v.y); o.z = f2bf(v.z); o.w = f2bf(v.w);
    dst[i] = o;
}

// src [K][N=2048] fp32 -> dst[n][colOff + k] bf16  (builds B^T = [Win;W]^T rows)
__global__ void transpose_bf16_kernel(const float* __restrict__ src, unsigned short* __restrict__ dst,
                                      int N, int ld, int colOff) {
    __shared__ float tile[32][33];
    int k0 = blockIdx.x * 32;
    int n0 = blockIdx.y * 32;
    int c = threadIdx.x & 31;
    int r = threadIdx.x >> 5;            // 0..7
    #pragma unroll
    for (int i = 0; i < 32; i += 8)
        tile[r + i][c] = src[(size_t)(k0 + r + i) * N + n0 + c];
    __syncthreads();
    #pragma unroll
    for (int i = 0; i < 32; i += 8)
        dst[(size_t)(n0 + r + i) * ld + colOff + k0 + c] = f2bf(tile[c][r + i]);
}

// h0 -> h_all slot 0 (bf16); lin_w -> padded bf16 [16][2048]; zero barrier slots
__global__ void small_conv_kernel(const float* __restrict__ h0, const float* __restrict__ lin_w,
                                  unsigned short* __restrict__ h_all0, unsigned short* __restrict__ lwb,
                                  unsigned int* __restrict__ bar) {
    int idx = blockIdx.x * 256 + threadIdx.x;
    if (idx < 512) bar[idx] = 0u;        // 256 slots + pad (re-zeroed every launch)
    if (idx < Bn * Hn) {
        h_all0[idx] = f2bf(h0[idx]);
    } else {
        int j = idx - Bn * Hn;           // < 16*2048 exactly (grid sized for it)
        int o = j >> 11;
        int k = j & 2047;
        lwb[j] = (o < On) ? f2bf(lin_w[o * Hn + k]) : (unsigned short)0;
    }
}

// ---- persistent scan -----------------------------------------------------
// 256 blocks x 512 thr (8 waves = 2/SIMD), 1 block/CU. Tile 64m x 32n;
// n XCD-swizzled via blockIdx%8 (B^T slice L2 locality). Compute loop = R5's
// best (plain chunk loads, compiler-scheduled; R6-R8 variants were neutral
// or regressed and are reverted).
//
// R9 barrier redesign (R8 exonerated the coherence path: FETCH/WRITE
// unchanged by per-XCD wbl2; remaining suspect is the barrier itself —
// 256 participants, serialized RMW arrivals, 2-hop master->epoch chain):
//  * SCOPE: h rows [m0,m0+64) are consumed only by the 64 blocks sharing
//    m0 -> 4 INDEPENDENT per-m-group barriers; groups drift freely, no
//    chip-wide straggler coupling.
//  * ARRIVAL: each block STOREs t+1 to its own slot (agent-scope relaxed
//    atomic store, write-through, no RMW serialization).
//  * DETECTION: one hop — wave 0 of each waiting block polls ALL 64 group
//    slots with a single 64-lane agent-scope atomic load + __ballot
//    (4 cache lines/round), s_sleep(1) between rounds.
// h stores: agent-scope relaxed atomic (write-through) as in R5 (proven);
// readers need no acquire (h[t+1] lines are first-touch per step).
__global__ __launch_bounds__(512, 2)
void scan_kernel(const unsigned short* __restrict__ xb,
                 const unsigned short* __restrict__ BTm,
                 unsigned short* __restrict__ h_all,
                 unsigned int* __restrict__ bar) {
    const int g = blockIdx.x;
    const int mgrp = (g >> 3) & 3;
    const int m0 = mgrp * 64;                           // 4 m-tiles
    const int nid = (g & 7) * 8 + (g >> 5);             // 0..63 within group
    const int n0 = nid * 32;                            // 64 n-tiles, XCD-swizzled
    const int w = threadIdx.x >> 6;                     // 0..7
    const int lane = threadIdx.x & 63;
    const int quad = lane >> 4;
    const int lr = lane & 15;

    __shared__ float red[4][64][36];                    // pad 36: 2-way banks (free)

    const unsigned short* bp0 = BTm + (size_t)(n0 + lr) * Kc;
    const unsigned short* bp1 = BTm + (size_t)(n0 + 16 + lr) * Kc;

    const size_t xrow = (size_t)Tn * In;                // x row stride (102400)

    unsigned int* myslot = bar + mgrp * 64 + nid;       // this block's arrival slot
    unsigned int* grpbase = bar + mgrp * 64;            // group's 64 slots (4 lines)

    // ---- one-time B-fragment preload (compiler may cache or re-load) ------
    s8v bx[4][2];                                       // x-region B frags
    s8v bh[8][2];                                       // h-region B frags
    #pragma unroll
    for (int c = 0; c < 4; ++c) {
        const int kq = w * 128 + c * 32 + quad * 8;
        bx[c][0] = *(const s8v*)(bp0 + kq);
        bx[c][1] = *(const s8v*)(bp1 + kq);
    }
    #pragma unroll
    for (int c = 0; c < 8; ++c) {
        const int kq = In + w * 256 + c * 32 + quad * 8;
        bh[c][0] = *(const s8v*)(bp0 + kq);
        bh[c][1] = *(const s8v*)(bp1 + kq);
    }

    f32x4 acc[4][2];
    #pragma unroll
    for (int mi = 0; mi < 4; ++mi)
        #pragma unroll
        for (int ni = 0; ni < 2; ++ni)
            acc[mi][ni] = (f32x4){0.f, 0.f, 0.f, 0.f};

    // ---- x-part for t=0 ----
    {
        const unsigned short* xt = xb;
        #pragma unroll
        for (int c = 0; c < 4; ++c) {
            const int kq = w * 128 + c * 32 + quad * 8;
            const unsigned short* arow = xt + kq + (size_t)(m0 + lr) * xrow;
            s8v a0 = *(const s8v*)(arow);
            s8v a1 = *(const s8v*)(arow + 16 * xrow);
            s8v a2 = *(const s8v*)(arow + 32 * xrow);
            s8v a3 = *(const s8v*)(arow + 48 * xrow);
            acc[0][0] = __builtin_amdgcn_mfma_f32_16x16x32_bf16(a0, bx[c][0], acc[0][0], 0, 0, 0);
            acc[1][0] = __builtin_amdgcn_mfma_f32_16x16x32_bf16(a1, bx[c][0], acc[1][0], 0, 0, 0);
            acc[2][0] = __builtin_amdgcn_mfma_f32_16x16x32_bf16(a2, bx[c][0], acc[2][0], 0, 0, 0);
            acc[3][0] = __builtin_amdgcn_mfma_f32_16x16x32_bf16(a3, bx[c][0], acc[3][0], 0, 0, 0);
            acc[0][1] = __builtin_amdgcn_mfma_f32_16x16x32_bf16(a0, bx[c][1], acc[0][1], 0, 0, 0);
            acc[1][1] = __builtin_amdgcn_mfma_f32_16x16x32_bf16(a1, bx[c][1], acc[1][1], 0, 0, 0);
            acc[2][1] = __builtin_amdgcn_mfma_f32_16x16x32_bf16(a2, bx[c][1], acc[2][1], 0, 0, 0);
            acc[3][1] = __builtin_amdgcn_mfma_f32_16x16x32_bf16(a3, bx[c][1], acc[3][1], 0, 0, 0);
        }
    }

    for (int t = 0; t < Tn; ++t) {
        // ---- h-part (gated on group barrier of step t-1) ----
        const unsigned short* hprev = h_all + (size_t)t * (Bn * Hn);
        #pragma unroll
        for (int c = 0; c < 8; ++c) {
            const int kq = w * 256 + c * 32 + quad * 8;            // offset inside h
            const unsigned short* arow = hprev + kq + (size_t)(m0 + lr) * Hn;
            s8v a0 = *(const s8v*)(arow);
            s8v a1 = *(const s8v*)(arow + 16 * Hn);
            s8v a2 = *(const s8v*)(arow + 32 * Hn);
            s8v a3 = *(const s8v*)(arow + 48 * Hn);
            acc[0][0] = __builtin_amdgcn_mfma_f32_16x16x32_bf16(a0, bh[c][0], acc[0][0], 0, 0, 0);
            acc[1][0] = __builtin_amdgcn_mfma_f32_16x16x32_bf16(a1, bh[c][0], acc[1][0], 0, 0, 0);
            acc[2][0] = __builtin_amdgcn_mfma_f32_16x16x32_bf16(a2, bh[c][0], acc[2][0], 0, 0, 0);
            acc[3][0] = __builtin_amdgcn_mfma_f32_16x16x32_bf16(a3, bh[c][0], acc[3][0], 0, 0, 0);
            acc[0][1] = __builtin_amdgcn_mfma_f32_16x16x32_bf16(a0, bh[c][1], acc[0][1], 0, 0, 0);
            acc[1][1] = __builtin_amdgcn_mfma_f32_16x16x32_bf16(a1, bh[c][1], acc[1][1], 0, 0, 0);
            acc[2][1] = __builtin_amdgcn_mfma_f32_16x16x32_bf16(a2, bh[c][1], acc[2][1], 0, 0, 0);
            acc[3][1] = __builtin_amdgcn_mfma_f32_16x16x32_bf16(a3, bh[c][1], acc[3][1], 0, 0, 0);
        }

        // ---- LDS reduce: C/D layout row=quad*4+reg, col=lane&15 [m89/m91] ----
        if (w < 4) {
            #pragma unroll
            for (int mi = 0; mi < 4; ++mi)
                #pragma unroll
                for (int ni = 0; ni < 2; ++ni)
                    #pragma unroll
                    for (int rr = 0; rr < 4; ++rr)
                        red[w][mi * 16 + quad * 4 + rr][ni * 16 + lr] = acc[mi][ni][rr];
        }
        __syncthreads();
        if (w >= 4) {
            #pragma unroll
            for (int mi = 0; mi < 4; ++mi)
                #pragma unroll
                for (int ni = 0; ni < 2; ++ni)
                    #pragma unroll
                    for (int rr = 0; rr < 4; ++rr)
                        red[w - 4][mi * 16 + quad * 4 + rr][ni * 16 + lr] += acc[mi][ni][rr];
        }
        __syncthreads();

        {   // final reduce + tanh + agent-scope write-through store (8 B)
            int j = threadIdx.x << 2;
            int row = j >> 5;
            int c0 = j & 31;
            float4 s0 = *(const float4*)&red[0][row][c0];
            float4 s1 = *(const float4*)&red[1][row][c0];
            float4 s2 = *(const float4*)&red[2][row][c0];
            float4 s3 = *(const float4*)&red[3][row][c0];
            us4 o4;
            o4[0] = f2bf(ftanh(s0.x + s1.x + s2.x + s3.x));
            o4[1] = f2bf(ftanh(s0.y + s1.y + s2.y + s3.y));
            o4[2] = f2bf(ftanh(s0.z + s1.z + s2.z + s3.z));
            o4[3] = f2bf(ftanh(s0.w + s1.w + s2.w + s3.w));
            unsigned long long* dst = (unsigned long long*)
                (h_all + (size_t)(t + 1) * (Bn * Hn) + (size_t)(m0 + row) * Hn + n0 + c0);
            __hip_atomic_store(dst, __builtin_bit_cast(unsigned long long, o4),
                               __ATOMIC_RELAXED, __HIP_MEMORY_SCOPE_AGENT);
        }

        if (t < Tn - 1) {
            // ---- cross-barrier fill: next step's x-part ----
            #pragma unroll
            for (int mi = 0; mi < 4; ++mi)
                #pragma unroll
                for (int ni = 0; ni < 2; ++ni)
                    acc[mi][ni] = (f32x4){0.f, 0.f, 0.f, 0.f};
            const unsigned short* xt = xb + (size_t)(t + 1) * In;
            #pragma unroll
            for (int c = 0; c < 4; ++c) {
                const int kq = w * 128 + c * 32 + quad * 8;
                const unsigned short* arow = xt + kq + (size_t)(m0 + lr) * xrow;
                s8v a0 = *(const s8v*)(arow);
                s8v a1 = *(const s8v*)(arow + 16 * xrow);
                s8v a2 = *(const s8v*)(arow + 32 * xrow);
                s8v a3 = *(const s8v*)(arow + 48 * xrow);
                acc[0][0] = __builtin_amdgcn_mfma_f32_16x16x32_bf16(a0, bx[c][0], acc[0][0], 0, 0, 0);
                acc[1][0] = __builtin_amdgcn_mfma_f32_16x16x32_bf16(a1, bx[c][0], acc[1][0], 0, 0, 0);
                acc[2][0] = __builtin_amdgcn_mfma_f32_16x16x32_bf16(a2, bx[c][0], acc[2][0], 0, 0, 0);
                acc[3][0] = __builtin_amdgcn_mfma_f32_16x16x32_bf16(a3, bx[c][0], acc[3][0], 0, 0, 0);
                acc[0][1] = __builtin_amdgcn_mfma_f32_16x16x32_bf16(a0, bx[c][1], acc[0][1], 0, 0, 0);
                acc[1][1] = __builtin_amdgcn_mfma_f32_16x16x32_bf16(a1, bx[c][1], acc[1][1], 0, 0, 0);
                acc[2][1] = __builtin_amdgcn_mfma_f32_16x16x32_bf16(a2, bx[c][1], acc[2][1], 0, 0, 0);
                acc[3][1] = __builtin_amdgcn_mfma_f32_16x16x32_bf16(a3, bx[c][1], acc[3][1], 0, 0, 0);
            }

            __syncthreads();                             // all waves' h stores drained (vmcnt0)
            if (threadIdx.x == 0)                        // arrival: plain slot store, no RMW
                __hip_atomic_store(myslot, (unsigned int)(t + 1),
                                   __ATOMIC_RELAXED, __HIP_MEMORY_SCOPE_AGENT);
            if (w == 0) {                                // 64-lane ballot poll of group slots
                const unsigned int tp1 = (unsigned int)(t + 1);
                unsigned int* s = grpbase + lane;
                for (;;) {
                    unsigned int v = __hip_atomic_load(s, __ATOMIC_RELAXED,
                                                       __HIP_MEMORY_SCOPE_AGENT);
                    if (__ballot(v < tp1) == 0ull) break;
                    __builtin_amdgcn_s_sleep(1);
                }
            }
            __syncthreads();
        }
    }
}

// ---- output projection ---------------------------------------------------
// y[b][t][o] = h_all[t+1][b][:] . lin_w[o][:] + lin_b[o]. One 16-row wave per 16 (t,b) rows.
__global__ __launch_bounds__(256)
void gemm2_kernel(const unsigned short* __restrict__ h_all, const unsigned short* __restrict__ lwb,
                  const float* __restrict__ lb, float* __restrict__ y) {
    int gw = blockIdx.x * 4 + (threadIdx.x >> 6);       // 0..1599
    int lane = threadIdx.x & 63, quad = lane >> 4, lr = lane & 15;
    int m0 = gw * 16;
    int t = m0 >> 8;
    int b0 = m0 & 255;
    const unsigned short* ah = h_all + ((size_t)(t + 1) * Bn + b0 + lr) * Hn + quad * 8;
    const unsigned short* bh = lwb + (size_t)lr * Hn + quad * 8;
    f32x4 acc0 = {0.f, 0.f, 0.f, 0.f}, acc1 = {0.f, 0.f, 0.f, 0.f};
    #pragma unroll
    for (int k0 = 0; k0 < Hn; k0 += 64) {
        s8v a0 = *(const s8v*)(ah + k0);
        s8v b0 = *(const s8v*)(bh + k0);
        acc0 = __builtin_amdgcn_mfma_f32_16x16x32_bf16(a0, b0, acc0, 0, 0, 0);
        s8v a1 = *(const s8v*)(ah + k0 + 32);
        s8v b1 = *(const s8v*)(bh + k0 + 32);
        acc1 = __builtin_amdgcn_mfma_f32_16x16x32_bf16(a1, b1, acc1, 0, 0, 0);
    }
    acc0 = acc0 + acc1;
    if (lr < On) {
        float bias = lb[lr];
        #pragma unroll
        for (int rr = 0; rr < 4; ++rr) {
            int b = b0 + quad * 4 + rr;
            y[(size_t)b * (Tn * On) + t * On + lr] = acc0[rr] + bias;
        }
    }
}

// ---- host ----------------------------------------------------------------

extern "C" void kernel_launch(void* const* d_in, const int* in_sizes, int n_in,
                              void* d_out, int out_size, void* d_ws, size_t ws_size,
                              hipStream_t stream) {
    const float* x   = (const float*)d_in[0];
    const float* h0  = (const float*)d_in[1];
    const float* Win = (const float*)d_in[2];
    const float* W   = (const float*)d_in[3];
    const float* lw  = (const float*)d_in[4];
    const float* lb  = (const float*)d_in[5];
    float* y = (float*)d_out;

    // ws layout (bf16 elems): ~171 MB total
    unsigned short* ws    = (unsigned short*)d_ws;
    unsigned short* xb    = ws;                                  // 26,214,400 elems
    unsigned short* BTm   = xb + (size_t)Bn * Tn * In;           //  6,291,456 elems [2048][3072]
    unsigned short* h_all = BTm + (size_t)Hn * Kc;               // 52,953,088 elems [(T+1)][B][H]
    unsigned short* lwb   = h_all + (size_t)(Tn + 1) * Bn * Hn;  //     32,768 elems [16][2048]
    unsigned int*   bar   = (unsigned int*)(lwb + 32768);        // 256 arrival slots (+pad)

    conv_x_kernel<<<25600, 256, 0, stream>>>((const float4*)x, (ushort4*)xb);
    transpose_bf16_kernel<<<dim3(32, 64), 256, 0, stream>>>(Win, BTm, Hn, Kc, 0);
    transpose_bf16_kernel<<<dim3(64, 64), 256, 0, stream>>>(W, BTm, Hn, Kc, In);
    small_conv_kernel<<<2176, 256, 0, stream>>>(h0, lw, h_all, lwb, bar);

    scan_kernel<<<256, 512, 0, stream>>>(xb, BTm, h_all, bar);

    gemm2_kernel<<<400, 256, 0, stream>>>(h_all, lwb, lb, y);
}